// Round 4
// baseline (926.837 us; speedup 1.0000x reference)
//
#include <hip/hip_runtime.h>
#include <float.h>

#define NROWS 32768   // B*S = 8*4096
#define KDIM  512
#define NEMB  4096

#define NCB_FAST 16   // 256-wide code blocks (fast path)
#define NCB_SLOW 32   // 128-wide (fallback path)

// ---- ws layout (float units) ----
#define OFF_NORMS 0u
#define OFF_ET    4096u
#define OFF_PART  (OFF_ET + 2097152u)         // float2: NROWS*32 max
#define OFF_IDX   (OFF_PART + 2097152u)
#define OFF_DP    (OFF_IDX + 32768u)
#define OFF_XHI   (OFF_DP + 2048u)            // shorts: NROWS*KDIM
#define OFF_XLO   (OFF_XHI + 8388608u)
#define OFF_EHI   (OFF_XLO + 8388608u)        // shorts: NEMB*KDIM
#define OFF_ELO   (OFF_EHI + 1048576u)
#define WS_FAST_FLOATS (OFF_ELO + 1048576u)   // ~92.4 MB
// ---- out layout (float units) ----
#define OUT_Q    0u
#define OUT_DIFF 16777216u
#define OUT_IDX  16777217u

typedef __attribute__((ext_vector_type(8))) short bf16x8;
typedef __attribute__((ext_vector_type(4))) float f32x4;

static __device__ inline unsigned short f2bf(float f) {
    unsigned u = __float_as_uint(f);
    unsigned r = (u + 0x7FFFu + ((u >> 16) & 1u)) >> 16;   // RNE
    return (unsigned short)r;
}
static __device__ inline float bf2f(unsigned short b) {
    return __uint_as_float(((unsigned)b) << 16);
}

// ---------------- kernel 1: code norms ||e_j||^2 ----------------
__global__ __launch_bounds__(256) void k_norms(const float* __restrict__ e,
                                               float* __restrict__ norms) {
    int j = blockIdx.x * 256 + threadIdx.x;
    float s = 0.f;
    for (int k = 0; k < KDIM; ++k) {
        float v = e[(size_t)k * NEMB + j];
        s += v * v;
    }
    norms[j] = s;
}

// ---------------- kernel 2: transpose + hi/lo split of embed ----------------
__global__ void k_split_et(const float* __restrict__ e, float* __restrict__ et,
                           unsigned short* __restrict__ ehi, unsigned short* __restrict__ elo) {
    __shared__ float t[32][33];
    int jb = blockIdx.x * 32, kb = blockIdx.y * 32;
    int tx = threadIdx.x, ty = threadIdx.y;
    for (int i = ty; i < 32; i += 8)
        t[i][tx] = e[(size_t)(kb + i) * NEMB + jb + tx];
    __syncthreads();
    for (int i = ty; i < 32; i += 8) {
        float v = t[tx][i];
        size_t o = (size_t)(jb + i) * KDIM + kb + tx;
        et[o] = v;
        unsigned short h = f2bf(v);
        ehi[o] = h;
        elo[o] = f2bf(v - bf2f(h));
    }
}

// ---------------- kernel 3: hi/lo split of x ----------------
__global__ __launch_bounds__(256) void k_split_x(const float* __restrict__ x,
                                                 unsigned short* __restrict__ xhi,
                                                 unsigned short* __restrict__ xlo) {
    size_t i = ((size_t)blockIdx.x * 256 + threadIdx.x) * 4;
    float4 v = *(const float4*)(x + i);
    ushort4 h, l;
    h.x = f2bf(v.x); l.x = f2bf(v.x - bf2f(h.x));
    h.y = f2bf(v.y); l.y = f2bf(v.y - bf2f(h.y));
    h.z = f2bf(v.z); l.z = f2bf(v.z - bf2f(h.z));
    h.w = f2bf(v.w); l.w = f2bf(v.w - bf2f(h.w));
    *(ushort4*)(xhi + i) = h;
    *(ushort4*)(xlo + i) = l;
}

// ---------------- kernel 4: 256^2 8-phase split-bf16 MFMA GEMM + argmin ----------------
// 2048 blocks (XCD supertiled), 512 threads = 8 waves (2 wr x 4 wc).
// K' = 2048 = 32 K-tiles of 64; K-tile T: seg = T>>3 (A: xh,xh,xl,xl / B: eh,el,eh,el),
// k0 = (T&7)*64. Even K-tiles -> LDS buf0, odd -> buf1.
// Per iter (2 K-tiles): 8 phases; per phase {ds_read frags | stage 8KB strips | barrier |
// 16 MFMA (setprio) | barrier}. vmcnt(4) only at phases 4 and 8.
// Swizzle: 16B chunk c stored at c^(row&7) on BOTH gload source and ds_read (involution).
__global__ __launch_bounds__(512, 2) void k_mfma_argmin(
        const unsigned short* __restrict__ xhi, const unsigned short* __restrict__ xlo,
        const unsigned short* __restrict__ ehi, const unsigned short* __restrict__ elo,
        const float* __restrict__ norms, float2* __restrict__ part)
{
    __shared__ short lds_s[65536];      // 128 KB: A[d] at d*16384, B[d] at 32768+d*16384
    __shared__ float2 red[256][4];      // 8 KB epilogue

    const int tid = threadIdx.x;
    const int wid = tid >> 6, ln = tid & 63;
    const int wr = wid >> 2, wc = wid & 3;
    const int lr = ln & 15, hg = ln >> 4, lr7 = lr & 7;

    // XCD supertile: 8 XCDs x (16 rb inner x 16 cb outer)
    const int orig = blockIdx.x;             // 0..2047
    const int xcd = orig & 7;
    const int local = orig >> 3;
    const int rb = xcd * 16 + (local & 15);  // 0..127
    const int cb = local >> 4;               // 0..15
    const int row0 = rb * 256, col0 = cb * 256;

    // staging thread geometry: thread covers chunk (rq = tid>>3 row-in-strip, tid&7 col)
    const int rq = tid >> 3;
    const int cswz = ((tid & 7) ^ (rq & 7)) * 8;       // swizzled source chunk, elements
    const int baseb = rq + (rq & 32);                  // B two-run row offset

#define GLL(srcp, dstp) __builtin_amdgcn_global_load_lds( \
        (const __attribute__((address_space(1))) void*)(srcp), \
        (__attribute__((address_space(3))) void*)(dstp), 16, 0, 0)

    // A[mh] region of K-tile T: LDS rows {mh*64..+64, 128+mh*64..+64}; 2 instrs
    auto stageA = [&](int T, int mh) {
        const unsigned short* src = ((T >> 3) < 2) ? xhi : xlo;
        int d = T & 1, k0 = (T & 7) * 64;
        int s0 = mh * 64, s1 = 128 + mh * 64;
        GLL(src + (size_t)(row0 + s0 + rq) * KDIM + k0 + cswz,
            &lds_s[d * 16384 + s0 * 64 + tid * 8]);
        GLL(src + (size_t)(row0 + s1 + rq) * KDIM + k0 + cswz,
            &lds_s[d * 16384 + s1 * 64 + tid * 8]);
    };
    // B[nh] region: LDS rows {wc*64 + nh*32 ..+32} for wc=0..3; 2 instrs (rounds of 64 rows)
    auto stageB = [&](int T, int nh) {
        const unsigned short* src = ((T >> 3) & 1) ? elo : ehi;
        int d = T & 1, k0 = (T & 7) * 64;
        int br0 = nh * 32 + baseb;           // covers rows nh*32.. and 64+nh*32..
        int br1 = 128 + nh * 32 + baseb;     // covers rows 128+.. and 192+..
        GLL(src + (size_t)(col0 + br0) * KDIM + k0 + cswz,
            &lds_s[32768 + d * 16384 + br0 * 64 + (tid & 7) * 8]);
        GLL(src + (size_t)(col0 + br1) * KDIM + k0 + cswz,
            &lds_s[32768 + d * 16384 + br1 * 64 + (tid & 7) * 8]);
    };

    f32x4 acc[8][4];
#pragma unroll
    for (int m = 0; m < 8; ++m)
#pragma unroll
        for (int n = 0; n < 4; ++n) acc[m][n] = (f32x4){0.f, 0.f, 0.f, 0.f};

    bf16x8 a[4][2], b0[2][2], b1[2][2];

#define LDA(D, MH) { _Pragma("unroll") for (int mm = 0; mm < 4; ++mm) \
    _Pragma("unroll") for (int ks = 0; ks < 2; ++ks) \
        a[mm][ks] = *(const bf16x8*)&lds_s[(D) * 16384 + \
            (wr * 128 + (MH) * 64 + mm * 16 + lr) * 64 + (((ks * 4 + hg) ^ lr7) * 8)]; }
#define LDB(D, NH, BF) { _Pragma("unroll") for (int nn = 0; nn < 2; ++nn) \
    _Pragma("unroll") for (int ks = 0; ks < 2; ++ks) \
        BF[nn][ks] = *(const bf16x8*)&lds_s[32768 + (D) * 16384 + \
            (wc * 64 + (NH) * 32 + nn * 16 + lr) * 64 + (((ks * 4 + hg) ^ lr7) * 8)]; }
#define MFMA_PHASE(MH, NH, BF) { __builtin_amdgcn_s_setprio(1); \
    _Pragma("unroll") for (int mm = 0; mm < 4; ++mm) \
    _Pragma("unroll") for (int nn = 0; nn < 2; ++nn) \
    _Pragma("unroll") for (int ks = 0; ks < 2; ++ks) \
        acc[(MH) * 4 + mm][(NH) * 2 + nn] = __builtin_amdgcn_mfma_f32_16x16x32_bf16( \
            a[mm][ks], BF[nn][ks], acc[(MH) * 4 + mm][(NH) * 2 + nn], 0, 0, 0); \
    __builtin_amdgcn_s_setprio(0); }
#define BAR() __builtin_amdgcn_s_barrier()

    // prologue: K0 full (8 instrs), K1 A[mh0]+B[nh0] (4 instrs)
    stageA(0, 0); stageB(0, 0); stageA(0, 1); stageB(0, 1);
    stageA(1, 0); stageB(1, 0);
    asm volatile("s_waitcnt vmcnt(4)" ::: "memory");   // K0 landed
    BAR();

#pragma unroll 1
    for (int i = 0; i < 16; ++i) {
        const int t = 2 * i;
        const bool s2 = (t + 2) < 32, s3 = (t + 3) < 32;
        // phase 1: (mh0,nh0) buf0 | stage A[mh1]+B[nh1] of t+1 -> buf1 (dead since prev ph8)
        LDA(0, 0); LDB(0, 0, b0);
        stageA(t + 1, 1); stageB(t + 1, 1);
        BAR(); MFMA_PHASE(0, 0, b0); BAR();
        // phase 2: (mh0,nh1) buf0
        LDB(0, 1, b1);
        BAR(); MFMA_PHASE(0, 1, b1); BAR();
        // phase 3: (mh1,nh0) buf0 | stage A[mh0] of t+2 -> buf0 (dead since ph2)
        LDA(0, 1);
        if (s2) stageA(t + 2, 0);
        BAR(); MFMA_PHASE(1, 0, b0); BAR();
        // phase 4: (mh1,nh1) buf0 | stage B[nh0] of t+2 (dead since ph3) | vmcnt
        if (s2) {
            stageB(t + 2, 0);
            asm volatile("s_waitcnt vmcnt(4)" ::: "memory");   // t+1 complete
        } else {
            asm volatile("s_waitcnt vmcnt(0)" ::: "memory");   // tail: drain t+1
        }
        BAR(); MFMA_PHASE(1, 1, b1); BAR();
        // phase 5: (mh0,nh0) buf1 | stage A[mh1]+B[nh1] of t+2 -> buf0 (dead since ph4)
        LDA(1, 0); LDB(1, 0, b0);
        if (s2) { stageA(t + 2, 1); stageB(t + 2, 1); }
        BAR(); MFMA_PHASE(0, 0, b0); BAR();
        // phase 6: (mh0,nh1) buf1
        LDB(1, 1, b1);
        BAR(); MFMA_PHASE(0, 1, b1); BAR();
        // phase 7: (mh1,nh0) buf1 | stage A[mh0] of t+3 -> buf1 (dead since ph6)
        LDA(1, 1);
        if (s3) stageA(t + 3, 0);
        BAR(); MFMA_PHASE(1, 0, b0); BAR();
        // phase 8: (mh1,nh1) buf1 | stage B[nh0] of t+3 (dead since ph7) | vmcnt
        if (s3) stageB(t + 3, 0);
        asm volatile("s_waitcnt vmcnt(4)" ::: "memory");       // t+2 complete
        BAR(); MFMA_PHASE(1, 1, b1); BAR();
    }
#undef LDA
#undef LDB
#undef MFMA_PHASE
#undef BAR
#undef GLL

    // epilogue: score = norms[col] - 2*dot ; argmin, first-index tie-break
    float nrm[4];
#pragma unroll
    for (int n = 0; n < 4; ++n) nrm[n] = norms[col0 + wc * 64 + n * 16 + lr];

#pragma unroll
    for (int m = 0; m < 8; ++m)
#pragma unroll
        for (int r = 0; r < 4; ++r) {
            float bs = FLT_MAX;
            int bc = 0x7FFFFFFF;
#pragma unroll
            for (int n = 0; n < 4; ++n) {
                float s = nrm[n] - 2.f * acc[m][n][r];
                int c = wc * 64 + n * 16 + lr;
                if (s < bs || (s == bs && c < bc)) { bs = s; bc = c; }
            }
#pragma unroll
            for (int off = 1; off < 16; off <<= 1) {
                float os = __shfl_xor(bs, off, 64);
                int oc = __shfl_xor(bc, off, 64);
                if (os < bs || (os == bs && oc < bc)) { bs = os; bc = oc; }
            }
            if (lr == 0)
                red[wr * 128 + m * 16 + hg * 4 + r][wc] = make_float2(bs, __int_as_float(bc));
        }
    __syncthreads();
    if (tid < 256) {
        float bs = FLT_MAX;
        int bc = 0x7FFFFFFF;
#pragma unroll
        for (int w = 0; w < 4; ++w) {          // ascending wc = ascending code index
            float2 p = red[tid][w];
            int c = __float_as_int(p.y);
            if (p.x < bs || (p.x == bs && c < bc)) { bs = p.x; bc = c; }
        }
        part[(size_t)(row0 + tid) * NCB_FAST + cb] =
            make_float2(bs, __int_as_float(col0 + bc));
    }
}

// ---------------- fallback fp32 GEMM-argmin (ws-lean) ----------------
#define TMF 128
#define TNF 128
#define TKF 16
__global__ __launch_bounds__(256) void k_gemm_argmin(
        const float* __restrict__ x, const float* __restrict__ e,
        const float* __restrict__ norms, float2* __restrict__ part)
{
    __shared__ float xs[TKF][132];
    __shared__ float es[TKF][TNF];
    __shared__ float2 red[TMF][16];

    const int row0 = blockIdx.x * TMF, col0 = blockIdx.y * TNF;
    const int tid = threadIdx.x;
    const int ty = tid >> 4, tx = tid & 15;

    float acc[8][8];
#pragma unroll
    for (int i = 0; i < 8; ++i)
#pragma unroll
        for (int j = 0; j < 8; ++j) acc[i][j] = 0.f;

    for (int k0 = 0; k0 < KDIM; k0 += TKF) {
        __syncthreads();
#pragma unroll
        for (int s = 0; s < 2; ++s) {
            int slot = tid + s * 256;
            int r = slot >> 2, c4 = slot & 3;
            float4 v = *(const float4*)(x + (size_t)(row0 + r) * KDIM + k0 + c4 * 4);
            xs[c4 * 4 + 0][r] = v.x; xs[c4 * 4 + 1][r] = v.y;
            xs[c4 * 4 + 2][r] = v.z; xs[c4 * 4 + 3][r] = v.w;
        }
#pragma unroll
        for (int s = 0; s < 2; ++s) {
            int slot = tid + s * 256;
            int k = slot >> 5, c4 = slot & 31;
            *(float4*)(&es[k][c4 * 4]) =
                *(const float4*)(e + (size_t)(k0 + k) * NEMB + col0 + c4 * 4);
        }
        __syncthreads();
#pragma unroll
        for (int k = 0; k < TKF; ++k) {
            float xv[8], ev[8];
            *(float4*)&xv[0] = *(const float4*)&xs[k][ty * 8];
            *(float4*)&xv[4] = *(const float4*)&xs[k][ty * 8 + 4];
            *(float4*)&ev[0] = *(const float4*)&es[k][tx * 8];
            *(float4*)&ev[4] = *(const float4*)&es[k][tx * 8 + 4];
#pragma unroll
            for (int i = 0; i < 8; ++i)
#pragma unroll
                for (int j = 0; j < 8; ++j) acc[i][j] += xv[i] * ev[j];
        }
    }
    float nrm[8];
#pragma unroll
    for (int j = 0; j < 8; ++j) nrm[j] = norms[col0 + tx * 8 + j];
#pragma unroll
    for (int i = 0; i < 8; ++i) {
        float best = FLT_MAX; int bj = 0;
#pragma unroll
        for (int j = 0; j < 8; ++j) {
            float sc = nrm[j] - 2.f * acc[i][j];
            if (sc < best) { best = sc; bj = tx * 8 + j; }
        }
        red[ty * 8 + i][tx] = make_float2(best, __int_as_float(bj));
    }
    __syncthreads();
    if (tid < TMF) {
        float best = FLT_MAX; int bj = 0;
        for (int t = 0; t < 16; ++t) {
            float2 p = red[tid][t];
            if (p.x < best) { best = p.x; bj = __float_as_int(p.y); }
        }
        part[(size_t)(row0 + tid) * NCB_SLOW + blockIdx.y] =
            make_float2(best, __int_as_float(col0 + bj));
    }
}

__global__ void k_transpose(const float* __restrict__ e, float* __restrict__ et) {
    __shared__ float t[32][33];
    int jb = blockIdx.x * 32, kb = blockIdx.y * 32;
    int tx = threadIdx.x, ty = threadIdx.y;
    for (int i = ty; i < 32; i += 8)
        t[i][tx] = e[(size_t)(kb + i) * NEMB + jb + tx];
    __syncthreads();
    for (int i = ty; i < 32; i += 8)
        et[(size_t)(jb + i) * KDIM + kb + tx] = t[tx][i];
}

// ---------------- kernel 5: reduce partial argmins ----------------
__global__ __launch_bounds__(256) void k_reduce(const float2* __restrict__ part, int ncb,
                                                int* __restrict__ idx_out,
                                                float* __restrict__ out) {
    int row = blockIdx.x * 256 + threadIdx.x;
    float best = FLT_MAX;
    int bj = 0x7FFFFFFF;
    for (int cbi = 0; cbi < ncb; ++cbi) {   // ascending = ascending code index
        float2 p = part[(size_t)row * ncb + cbi];
        int c = __float_as_int(p.y);
        if (p.x < best || (p.x == best && c < bj)) { best = p.x; bj = c; }
    }
    idx_out[row] = bj;
    out[OUT_IDX + row] = (float)bj;
}

// ---------------- kernel 6: gather quantize + diff partials ----------------
__global__ __launch_bounds__(256) void k_gather(const float* __restrict__ x,
                                                const float* __restrict__ et,
                                                const int* __restrict__ idx,
                                                float* __restrict__ out,
                                                float* __restrict__ dpart) {
    const int b = blockIdx.x;
    const int tid = threadIdx.x;
    const int row0 = b * 16;
    float s = 0.f;
    for (int i = tid; i < 16 * KDIM; i += 256) {
        int r = i >> 9;
        int k = i & (KDIM - 1);
        int row = row0 + r;
        float q = et[(size_t)idx[row] * KDIM + k];
        float xv = x[(size_t)row * KDIM + k];
        float d = q - xv;
        s += d * d;
        out[OUT_Q + (size_t)row * KDIM + k] = q;
    }
#pragma unroll
    for (int off = 32; off >= 1; off >>= 1) s += __shfl_down(s, off, 64);
    __shared__ float ws_[4];
    int lane = tid & 63, wvi = tid >> 6;
    if (lane == 0) ws_[wvi] = s;
    __syncthreads();
    if (tid == 0) dpart[b] = ws_[0] + ws_[1] + ws_[2] + ws_[3];
}

// ---------------- kernel 7: final diff ----------------
__global__ __launch_bounds__(256) void k_diff(const float* __restrict__ dpart,
                                              float* __restrict__ out) {
    int tid = threadIdx.x;
    float s = 0.f;
    for (int i = tid; i < 2048; i += 256) s += dpart[i];
#pragma unroll
    for (int off = 32; off >= 1; off >>= 1) s += __shfl_down(s, off, 64);
    __shared__ float ws_[4];
    int lane = tid & 63, wvi = tid >> 6;
    if (lane == 0) ws_[wvi] = s;
    __syncthreads();
    if (tid == 0) out[OUT_DIFF] = (ws_[0] + ws_[1] + ws_[2] + ws_[3]) / 16777216.f;
}

extern "C" void kernel_launch(void* const* d_in, const int* in_sizes, int n_in,
                              void* d_out, int out_size, void* d_ws, size_t ws_size,
                              hipStream_t stream) {
    const float* x = (const float*)d_in[0];   // [8,4096,512]
    const float* e = (const float*)d_in[1];   // [512,4096]
    float* out = (float*)d_out;
    float* ws = (float*)d_ws;

    float*  norms = ws + OFF_NORMS;
    float*  et    = ws + OFF_ET;
    float2* part  = (float2*)(ws + OFF_PART);
    int*    idx   = (int*)(ws + OFF_IDX);
    float*  dpart = ws + OFF_DP;

    k_norms<<<NEMB / 256, 256, 0, stream>>>(e, norms);

    if (ws_size >= (size_t)WS_FAST_FLOATS * 4) {
        unsigned short* xhi = (unsigned short*)(ws + OFF_XHI);
        unsigned short* xlo = (unsigned short*)(ws + OFF_XLO);
        unsigned short* ehi = (unsigned short*)(ws + OFF_EHI);
        unsigned short* elo = (unsigned short*)(ws + OFF_ELO);
        k_split_et<<<dim3(NEMB / 32, KDIM / 32), dim3(32, 8), 0, stream>>>(e, et, ehi, elo);
        k_split_x<<<(NROWS * KDIM) / (256 * 4), 256, 0, stream>>>(x, xhi, xlo);
        k_mfma_argmin<<<2048, 512, 0, stream>>>(xhi, xlo, ehi, elo, norms, part);
        k_reduce<<<NROWS / 256, 256, 0, stream>>>(part, NCB_FAST, idx, out);
    } else {
        k_transpose<<<dim3(NEMB / 32, KDIM / 32), dim3(32, 8), 0, stream>>>(e, et);
        k_gemm_argmin<<<dim3(NROWS / TMF, NEMB / TNF), 256, 0, stream>>>(x, e, norms, part);
        k_reduce<<<NROWS / 256, 256, 0, stream>>>(part, NCB_SLOW, idx, out);
    }

    k_gather<<<NROWS / 16, 256, 0, stream>>>(x, et, idx, out, dpart);
    k_diff<<<1, 256, 0, stream>>>(dpart, out);
}

// Round 5
// 419.486 us; speedup vs baseline: 2.2095x; 2.2095x over previous
//
#include <hip/hip_runtime.h>
#include <float.h>

#define NROWS 32768   // B*S = 8*4096
#define KDIM  512
#define NEMB  4096

#define NCB 32        // 128-wide code blocks
#define MARGIN 2.0f   // hi-score candidate margin (~20 sigma of per-code err)

// ---- ws layout (float units) ----
#define OFF_NORMS 0u
#define OFF_ET    4096u
#define OFF_PART  (OFF_ET + 2097152u)          // float4 top2: NROWS*NCB
#define OFF_IDX   (OFF_PART + 4194304u)
#define OFF_DP    (OFF_IDX + 32768u)
#define OFF_XHI   (OFF_DP + 2048u)             // shorts: NROWS*KDIM
#define OFF_EHI   (OFF_XHI + 8388608u)         // shorts: NEMB*KDIM
#define WS_FAST_FLOATS (OFF_EHI + 1048576u)    // ~63.1 MB
// ---- out layout (float units) ----
#define OUT_Q    0u
#define OUT_DIFF 16777216u
#define OUT_IDX  16777217u

typedef __attribute__((ext_vector_type(8))) short bf16x8;
typedef __attribute__((ext_vector_type(4))) float f32x4;

static __device__ inline unsigned short f2bf(float f) {
    unsigned u = __float_as_uint(f);
    unsigned r = (u + 0x7FFFu + ((u >> 16) & 1u)) >> 16;   // RNE
    return (unsigned short)r;
}

static __device__ inline bool better(float s, int i, float t, int j) {
    return s < t || (s == t && i < j);
}
// merge sorted-2 (s0,i0,s1,i1) with other sorted-2 -> two smallest of union
static __device__ inline void t2_merge(float& s0, int& i0, float& s1, int& i1,
                                       float os0, int oi0, float os1, int oi1) {
    if (better(os0, oi0, s0, i0)) {
        float ns1; int ni1;
        if (better(s0, i0, os1, oi1)) { ns1 = s0; ni1 = i0; }
        else { ns1 = os1; ni1 = oi1; }
        s0 = os0; i0 = oi0; s1 = ns1; i1 = ni1;
    } else if (better(os0, oi0, s1, i1)) {
        s1 = os0; i1 = oi0;
    }
}

// ---------------- kernel 1: code norms ||e_j||^2 (fp32, exact) ----------------
__global__ __launch_bounds__(256) void k_norms(const float* __restrict__ e,
                                               float* __restrict__ norms) {
    int j = blockIdx.x * 256 + threadIdx.x;
    float s = 0.f;
    for (int k = 0; k < KDIM; ++k) {
        float v = e[(size_t)k * NEMB + j];
        s += v * v;
    }
    norms[j] = s;
}

// ---------------- kernel 2: transpose embed + hi split ----------------
__global__ void k_split_et(const float* __restrict__ e, float* __restrict__ et,
                           unsigned short* __restrict__ ehi) {
    __shared__ float t[32][33];
    int jb = blockIdx.x * 32, kb = blockIdx.y * 32;
    int tx = threadIdx.x, ty = threadIdx.y;
    for (int i = ty; i < 32; i += 8)
        t[i][tx] = e[(size_t)(kb + i) * NEMB + jb + tx];
    __syncthreads();
    for (int i = ty; i < 32; i += 8) {
        float v = t[tx][i];
        size_t o = (size_t)(jb + i) * KDIM + kb + tx;
        et[o] = v;
        ehi[o] = f2bf(v);
    }
}

// ---------------- kernel 3: hi split of x ----------------
__global__ __launch_bounds__(256) void k_split_x(const float* __restrict__ x,
                                                 unsigned short* __restrict__ xhi) {
    size_t i = ((size_t)blockIdx.x * 256 + threadIdx.x) * 4;
    float4 v = *(const float4*)(x + i);
    ushort4 h;
    h.x = f2bf(v.x); h.y = f2bf(v.y); h.z = f2bf(v.z); h.w = f2bf(v.w);
    *(ushort4*)(xhi + i) = h;
}

// ---------------- kernel 4: hi-only MFMA GEMM + per-block TOP-2 ----------------
// Round-3 verified structure: 8192 blocks (XCD supertiles), 256 thr (4 waves 2x2),
// 128x128 tile, BK=32, 16 K-steps, both-sides 16B-chunk swizzle, global_load_lds dbuf.
__global__ __launch_bounds__(256) void k_mfma_argmin(
        const unsigned short* __restrict__ xhi, const unsigned short* __restrict__ ehi,
        const float* __restrict__ norms, float4* __restrict__ part)
{
    __shared__ short As[2][128 * 32];
    __shared__ short Bs[2][128 * 32];
    __shared__ float4 red[128][2];

    const int tid = threadIdx.x;
    const int wv = tid >> 6, ln = tid & 63;
    const int lr = ln & 15, hg = ln >> 4;
    const int wr = wv >> 1, wc = wv & 1;

    // XCD-aware supertile decode (round-3)
    const int orig = blockIdx.x;
    const int xcd = orig & 7;
    const int local = orig >> 3;
    const int srow = local & 7;
    const int scol = (local >> 3) & 3;
    const int sblk = local >> 5;
    const int rb = xcd * 32 + (sblk >> 3) * 8 + srow;
    const int cb = (sblk & 7) * 4 + scol;
    const int row0 = rb * 128, col0 = cb * 128;

    size_t aoff[2], boff[2];
#pragma unroll
    for (int i = 0; i < 2; ++i) {
        int slot = (i * 4 + wv) * 64 + ln;
        int r = slot >> 2;
        int cg = (slot & 3) ^ ((r >> 1) & 3);
        aoff[i] = (size_t)(row0 + r) * KDIM + cg * 8;
        boff[i] = (size_t)(col0 + r) * KDIM + cg * 8;
    }

    f32x4 acc[4][4];
#pragma unroll
    for (int m = 0; m < 4; ++m)
#pragma unroll
        for (int n = 0; n < 4; ++n) acc[m][n] = (f32x4){0.f, 0.f, 0.f, 0.f};

#define STAGE(buf, step)                                                            \
    do {                                                                            \
        int k0_ = (step) * 32;                                                      \
        _Pragma("unroll")                                                           \
        for (int i_ = 0; i_ < 2; ++i_) {                                            \
            __builtin_amdgcn_global_load_lds(                                       \
                (const __attribute__((address_space(1))) void*)(xhi + aoff[i_] + k0_), \
                (__attribute__((address_space(3))) void*)&As[buf][(i_ * 4 + wv) * 512], \
                16, 0, 0);                                                          \
            __builtin_amdgcn_global_load_lds(                                       \
                (const __attribute__((address_space(1))) void*)(ehi + boff[i_] + k0_), \
                (__attribute__((address_space(3))) void*)&Bs[buf][(i_ * 4 + wv) * 512], \
                16, 0, 0);                                                          \
        }                                                                           \
    } while (0)

    STAGE(0, 0);
    __syncthreads();
    int cur = 0;
    const int swz = (hg ^ ((lr >> 1) & 3)) * 8;
    for (int step = 0; step < 16; ++step) {
        if (step < 15) STAGE(cur ^ 1, step + 1);
        bf16x8 a[4], b[4];
#pragma unroll
        for (int m = 0; m < 4; ++m)
            a[m] = *(const bf16x8*)&As[cur][(wr * 64 + m * 16 + lr) * 32 + swz];
#pragma unroll
        for (int n = 0; n < 4; ++n)
            b[n] = *(const bf16x8*)&Bs[cur][(wc * 64 + n * 16 + lr) * 32 + swz];
#pragma unroll
        for (int m = 0; m < 4; ++m)
#pragma unroll
            for (int n = 0; n < 4; ++n)
                acc[m][n] = __builtin_amdgcn_mfma_f32_16x16x32_bf16(a[m], b[n], acc[m][n], 0, 0, 0);
        __syncthreads();
        cur ^= 1;
    }
#undef STAGE

    // epilogue: hi-score = norms[col] - 2*dot ; per-(row,block) TOP-2
    float nrm[4];
#pragma unroll
    for (int n = 0; n < 4; ++n) nrm[n] = norms[col0 + wc * 64 + n * 16 + lr];

#pragma unroll
    for (int m = 0; m < 4; ++m)
#pragma unroll
        for (int r = 0; r < 4; ++r) {
            float s0 = FLT_MAX, s1 = FLT_MAX;
            int i0 = 0x7FFFFFFF, i1 = 0x7FFFFFFF;
#pragma unroll
            for (int n = 0; n < 4; ++n) {
                float s = nrm[n] - 2.f * acc[m][n][r];
                int c = wc * 64 + n * 16 + lr;   // block-local col
                if (better(s, c, s0, i0)) { s1 = s0; i1 = i0; s0 = s; i0 = c; }
                else if (better(s, c, s1, i1)) { s1 = s; i1 = c; }
            }
#pragma unroll
            for (int off = 1; off < 16; off <<= 1) {
                float os0 = __shfl_xor(s0, off, 64);
                int oi0 = __shfl_xor(i0, off, 64);
                float os1 = __shfl_xor(s1, off, 64);
                int oi1 = __shfl_xor(i1, off, 64);
                t2_merge(s0, i0, s1, i1, os0, oi0, os1, oi1);
            }
            if (lr == 0)
                red[wr * 64 + m * 16 + hg * 4 + r][wc] =
                    make_float4(s0, __int_as_float(i0), s1, __int_as_float(i1));
        }
    __syncthreads();
    if (tid < 128) {
        float4 p0 = red[tid][0], p1 = red[tid][1];
        float s0 = p0.x, s1 = p0.z;
        int i0 = __float_as_int(p0.y), i1 = __float_as_int(p0.w);
        t2_merge(s0, i0, s1, i1, p1.x, __float_as_int(p1.y), p1.z, __float_as_int(p1.w));
        part[(size_t)(row0 + tid) * NCB + cb] =
            make_float4(s0, __int_as_float(col0 + i0), s1, __int_as_float(col0 + i1));
    }
}

// ---------------- kernel 5: exact fp32 refine of in-margin candidates ----------------
__global__ __launch_bounds__(256) void k_refine(const float* __restrict__ x,
                                                const float* __restrict__ et,
                                                const float* __restrict__ norms,
                                                const float4* __restrict__ part,
                                                int* __restrict__ idx_out,
                                                float* __restrict__ out) {
    const int row = blockIdx.x * 4 + (threadIdx.x >> 6);
    const int lane = threadIdx.x & 63;

    float xv[8];
    *(float4*)&xv[0] = *(const float4*)(x + (size_t)row * KDIM + lane * 8);
    *(float4*)&xv[4] = *(const float4*)(x + (size_t)row * KDIM + lane * 8 + 4);

    const float4* prow = part + (size_t)row * NCB;
    float m = FLT_MAX;
    for (int cbi = 0; cbi < NCB; ++cbi) m = fminf(m, prow[cbi].x);
    const float thr = m + MARGIN;

    float bs = FLT_MAX;
    int bj = 0x7FFFFFFF;
    for (int cbi = 0; cbi < NCB; ++cbi) {
        float4 p = prow[cbi];
#pragma unroll
        for (int t = 0; t < 2; ++t) {
            float sh = t ? p.z : p.x;
            int j = __float_as_int(t ? p.w : p.y);
            if (sh <= thr) {                       // wave-uniform branch
                const float* er = et + (size_t)j * KDIM + lane * 8;
                float ev[8];
                *(float4*)&ev[0] = *(const float4*)er;
                *(float4*)&ev[4] = *(const float4*)(er + 4);
                float d = 0.f;
#pragma unroll
                for (int q = 0; q < 8; ++q) d += xv[q] * ev[q];
#pragma unroll
                for (int off = 1; off < 64; off <<= 1) d += __shfl_xor(d, off, 64);
                float s = norms[j] - 2.f * d;      // exact fp32 score
                if (better(s, j, bs, bj)) { bs = s; bj = j; }
            }
        }
    }
    if (lane == 0) {
        idx_out[row] = bj;
        out[OUT_IDX + row] = (float)bj;
    }
}

// ---------------- fallback fp32 GEMM-argmin (ws-lean, round-1) ----------------
#define TMF 128
#define TNF 128
#define TKF 16
__global__ __launch_bounds__(256) void k_gemm_argmin(
        const float* __restrict__ x, const float* __restrict__ e,
        const float* __restrict__ norms, float2* __restrict__ part)
{
    __shared__ float xs[TKF][132];
    __shared__ float es[TKF][TNF];
    __shared__ float2 red[TMF][16];

    const int row0 = blockIdx.x * TMF, col0 = blockIdx.y * TNF;
    const int tid = threadIdx.x;
    const int ty = tid >> 4, tx = tid & 15;

    float acc[8][8];
#pragma unroll
    for (int i = 0; i < 8; ++i)
#pragma unroll
        for (int j = 0; j < 8; ++j) acc[i][j] = 0.f;

    for (int k0 = 0; k0 < KDIM; k0 += TKF) {
        __syncthreads();
#pragma unroll
        for (int s = 0; s < 2; ++s) {
            int slot = tid + s * 256;
            int r = slot >> 2, c4 = slot & 3;
            float4 v = *(const float4*)(x + (size_t)(row0 + r) * KDIM + k0 + c4 * 4);
            xs[c4 * 4 + 0][r] = v.x; xs[c4 * 4 + 1][r] = v.y;
            xs[c4 * 4 + 2][r] = v.z; xs[c4 * 4 + 3][r] = v.w;
        }
#pragma unroll
        for (int s = 0; s < 2; ++s) {
            int slot = tid + s * 256;
            int k = slot >> 5, c4 = slot & 31;
            *(float4*)(&es[k][c4 * 4]) =
                *(const float4*)(e + (size_t)(k0 + k) * NEMB + col0 + c4 * 4);
        }
        __syncthreads();
#pragma unroll
        for (int k = 0; k < TKF; ++k) {
            float xv[8], ev[8];
            *(float4*)&xv[0] = *(const float4*)&xs[k][ty * 8];
            *(float4*)&xv[4] = *(const float4*)&xs[k][ty * 8 + 4];
            *(float4*)&ev[0] = *(const float4*)&es[k][tx * 8];
            *(float4*)&ev[4] = *(const float4*)&es[k][tx * 8 + 4];
#pragma unroll
            for (int i = 0; i < 8; ++i)
#pragma unroll
                for (int j = 0; j < 8; ++j) acc[i][j] += xv[i] * ev[j];
        }
    }
    float nrm[8];
#pragma unroll
    for (int j = 0; j < 8; ++j) nrm[j] = norms[col0 + tx * 8 + j];
#pragma unroll
    for (int i = 0; i < 8; ++i) {
        float best = FLT_MAX; int bj = 0;
#pragma unroll
        for (int j = 0; j < 8; ++j) {
            float sc = nrm[j] - 2.f * acc[i][j];
            if (sc < best) { best = sc; bj = tx * 8 + j; }
        }
        red[ty * 8 + i][tx] = make_float2(best, __int_as_float(bj));
    }
    __syncthreads();
    if (tid < TMF) {
        float best = FLT_MAX; int bj = 0;
        for (int t = 0; t < 16; ++t) {
            float2 p = red[tid][t];
            if (p.x < best) { best = p.x; bj = __float_as_int(p.y); }
        }
        part[(size_t)(row0 + tid) * NCB + blockIdx.y] =
            make_float2(best, __int_as_float(col0 + bj));
    }
}

__global__ void k_transpose(const float* __restrict__ e, float* __restrict__ et) {
    __shared__ float t[32][33];
    int jb = blockIdx.x * 32, kb = blockIdx.y * 32;
    int tx = threadIdx.x, ty = threadIdx.y;
    for (int i = ty; i < 32; i += 8)
        t[i][tx] = e[(size_t)(kb + i) * NEMB + jb + tx];
    __syncthreads();
    for (int i = ty; i < 32; i += 8)
        et[(size_t)(jb + i) * KDIM + kb + tx] = t[tx][i];
}

__global__ __launch_bounds__(256) void k_reduce(const float2* __restrict__ part,
                                                int* __restrict__ idx_out,
                                                float* __restrict__ out) {
    int row = blockIdx.x * 256 + threadIdx.x;
    float best = FLT_MAX;
    int bj = 0x7FFFFFFF;
    for (int cbi = 0; cbi < NCB; ++cbi) {
        float2 p = part[(size_t)row * NCB + cbi];
        int c = __float_as_int(p.y);
        if (p.x < best || (p.x == best && c < bj)) { best = p.x; bj = c; }
    }
    idx_out[row] = bj;
    out[OUT_IDX + row] = (float)bj;
}

// ---------------- kernel 6: gather quantize + diff partials ----------------
__global__ __launch_bounds__(256) void k_gather(const float* __restrict__ x,
                                                const float* __restrict__ et,
                                                const int* __restrict__ idx,
                                                float* __restrict__ out,
                                                float* __restrict__ dpart) {
    const int b = blockIdx.x;
    const int tid = threadIdx.x;
    const int row0 = b * 16;
    float s = 0.f;
    for (int i = tid; i < 16 * KDIM; i += 256) {
        int r = i >> 9;
        int k = i & (KDIM - 1);
        int row = row0 + r;
        float q = et[(size_t)idx[row] * KDIM + k];
        float xv = x[(size_t)row * KDIM + k];
        float d = q - xv;
        s += d * d;
        out[OUT_Q + (size_t)row * KDIM + k] = q;
    }
#pragma unroll
    for (int off = 32; off >= 1; off >>= 1) s += __shfl_down(s, off, 64);
    __shared__ float ws_[4];
    int lane = tid & 63, wvi = tid >> 6;
    if (lane == 0) ws_[wvi] = s;
    __syncthreads();
    if (tid == 0) dpart[b] = ws_[0] + ws_[1] + ws_[2] + ws_[3];
}

// ---------------- kernel 7: final diff ----------------
__global__ __launch_bounds__(256) void k_diff(const float* __restrict__ dpart,
                                              float* __restrict__ out) {
    int tid = threadIdx.x;
    float s = 0.f;
    for (int i = tid; i < 2048; i += 256) s += dpart[i];
#pragma unroll
    for (int off = 32; off >= 1; off >>= 1) s += __shfl_down(s, off, 64);
    __shared__ float ws_[4];
    int lane = tid & 63, wvi = tid >> 6;
    if (lane == 0) ws_[wvi] = s;
    __syncthreads();
    if (tid == 0) out[OUT_DIFF] = (ws_[0] + ws_[1] + ws_[2] + ws_[3]) / 16777216.f;
}

extern "C" void kernel_launch(void* const* d_in, const int* in_sizes, int n_in,
                              void* d_out, int out_size, void* d_ws, size_t ws_size,
                              hipStream_t stream) {
    const float* x = (const float*)d_in[0];   // [8,4096,512]
    const float* e = (const float*)d_in[1];   // [512,4096]
    float* out = (float*)d_out;
    float* ws = (float*)d_ws;

    float*  norms = ws + OFF_NORMS;
    float*  et    = ws + OFF_ET;
    int*    idx   = (int*)(ws + OFF_IDX);
    float*  dpart = ws + OFF_DP;

    k_norms<<<NEMB / 256, 256, 0, stream>>>(e, norms);

    if (ws_size >= (size_t)WS_FAST_FLOATS * 4) {
        float4* part = (float4*)(ws + OFF_PART);
        unsigned short* xhi = (unsigned short*)(ws + OFF_XHI);
        unsigned short* ehi = (unsigned short*)(ws + OFF_EHI);
        k_split_et<<<dim3(NEMB / 32, KDIM / 32), dim3(32, 8), 0, stream>>>(e, et, ehi);
        k_split_x<<<(NROWS * KDIM) / (256 * 4), 256, 0, stream>>>(x, xhi);
        k_mfma_argmin<<<8192, 256, 0, stream>>>(xhi, ehi, norms, part);
        k_refine<<<NROWS / 4, 256, 0, stream>>>(x, et, norms, part, idx, out);
    } else {
        float2* part2 = (float2*)(ws + OFF_PART);
        k_transpose<<<dim3(NEMB / 32, KDIM / 32), dim3(32, 8), 0, stream>>>(e, et);
        k_gemm_argmin<<<dim3(NROWS / TMF, NEMB / TNF), 256, 0, stream>>>(x, e, norms, part2);
        k_reduce<<<NROWS / 256, 256, 0, stream>>>(part2, idx, out);
    }

    k_gather<<<NROWS / 16, 256, 0, stream>>>(x, et, idx, out, dpart);
    k_diff<<<1, 256, 0, stream>>>(dpart, out);
}

// Round 7
// 360.245 us; speedup vs baseline: 2.5728x; 1.1644x over previous
//
#include <hip/hip_runtime.h>
#include <float.h>

#define NROWS 32768   // B*S = 8*4096
#define KDIM  512
#define NEMB  4096

#define NCB 32        // 128-wide code blocks
#define MARGIN 2.0f   // hi-score candidate margin (~20 sigma of hi-score err)

// ---- ws layout (float units) ----
#define OFF_NORMS 0u
#define OFF_ET    4096u
#define OFF_PART  (OFF_ET + 2097152u)          // float4 top2: NROWS*NCB
#define OFF_IDX   (OFF_PART + 4194304u)        // fallback only
#define OFF_DP    (OFF_IDX + 32768u)           // 8192 partials
#define OFF_XHI   (OFF_DP + 8192u)             // shorts: NROWS*KDIM = 16,777,216 shorts
#define OFF_EHI   (OFF_XHI + 8388608u)         // = xhi float-units (8,388,608 floats!); shorts: NEMB*KDIM
#define WS_FAST_FLOATS (OFF_EHI + 524288u)     // ~61 MB
// ---- out layout (float units) ----
#define OUT_Q    0u
#define OUT_DIFF 16777216u
#define OUT_IDX  16777217u

typedef __attribute__((ext_vector_type(8))) short bf16x8;
typedef __attribute__((ext_vector_type(4))) float f32x4;
typedef unsigned long long ull;

static __device__ inline unsigned short f2bf(float f) {
    unsigned u = __float_as_uint(f);
    unsigned r = (u + 0x7FFFu + ((u >> 16) & 1u)) >> 16;   // RNE
    return (unsigned short)r;
}
// float -> order-preserving u32 (ascending float = ascending uint)
static __device__ inline unsigned f2s(float f) {
    unsigned u = __float_as_uint(f);
    return (u & 0x80000000u) ? ~u : (u | 0x80000000u);
}
static __device__ inline float s2f(unsigned su) {
    su = (su & 0x80000000u) ? (su ^ 0x80000000u) : ~su;
    return __uint_as_float(su);
}
static __device__ inline bool better(float s, int i, float t, int j) {
    return s < t || (s == t && i < j);
}

// ---------------- kernel 1: code norms ||e_j||^2 (fp32, exact) ----------------
__global__ __launch_bounds__(256) void k_norms(const float* __restrict__ e,
                                               float* __restrict__ norms) {
    int j = blockIdx.x * 256 + threadIdx.x;
    float s = 0.f;
    for (int k = 0; k < KDIM; ++k) {
        float v = e[(size_t)k * NEMB + j];
        s += v * v;
    }
    norms[j] = s;
}

// ---------------- kernel 2: transpose embed + hi split ----------------
__global__ void k_split_et(const float* __restrict__ e, float* __restrict__ et,
                           unsigned short* __restrict__ ehi) {
    __shared__ float t[32][33];
    int jb = blockIdx.x * 32, kb = blockIdx.y * 32;
    int tx = threadIdx.x, ty = threadIdx.y;
    for (int i = ty; i < 32; i += 8)
        t[i][tx] = e[(size_t)(kb + i) * NEMB + jb + tx];
    __syncthreads();
    for (int i = ty; i < 32; i += 8) {
        float v = t[tx][i];
        size_t o = (size_t)(jb + i) * KDIM + kb + tx;
        et[o] = v;
        ehi[o] = f2bf(v);
    }
}

// ---------------- kernel 3: hi split of x ----------------
__global__ __launch_bounds__(256) void k_split_x(const float* __restrict__ x,
                                                 unsigned short* __restrict__ xhi) {
    size_t i = ((size_t)blockIdx.x * 256 + threadIdx.x) * 4;
    float4 v = *(const float4*)(x + i);
    ushort4 h;
    h.x = f2bf(v.x); h.y = f2bf(v.y); h.z = f2bf(v.z); h.w = f2bf(v.w);
    *(ushort4*)(xhi + i) = h;
}

// ---------------- kernel 4: hi-only MFMA GEMM + per-128-block TOP-2 ----------------
// 4096 blocks (XCD supertiles), 256 thr = 4 waves (2 wr x 2 wc).
// Tile 128 rows x 256 cols; wave = 64 rows x 128 cols (= one code block) -> acc[4][8],
// direct part write, no cross-wave merge. BK=32, 16 K-steps, dbuf,
// both-sides 16B-chunk swizzle, global_load_lds(16).
__global__ __launch_bounds__(256) void k_mfma_argmin(
        const unsigned short* __restrict__ xhi, const unsigned short* __restrict__ ehi,
        const float* __restrict__ norms, float4* __restrict__ part)
{
    __shared__ short As[2][128 * 32];   // 8 KB / buf
    __shared__ short Bs[2][256 * 32];   // 16 KB / buf

    const int tid = threadIdx.x;
    const int wv = tid >> 6, ln = tid & 63;
    const int lr = ln & 15, hg = ln >> 4;
    const int wr = wv >> 1, wc = wv & 1;

    // XCD-aware supertile decode: 8 XCDs x [4 rb-bands x (8 rb x 4 cgrp)]
    const int orig = blockIdx.x;             // 0..4095
    const int xcd = orig & 7;
    const int local = orig >> 3;             // 0..511
    const int srow = local & 7;
    const int scol = (local >> 3) & 3;
    const int sblk = local >> 5;             // 0..15
    const int rb = xcd * 32 + (sblk >> 2) * 8 + srow;   // 0..255
    const int cgrp = (sblk & 3) * 4 + scol;             // 0..15
    const int row0 = rb * 128, col0 = cgrp * 256;

    // staging source offsets (swizzled chunk: cg ^= (r>>1)&3)
    size_t aoff[2], boff[4];
#pragma unroll
    for (int i = 0; i < 2; ++i) {
        int slot = (i * 4 + wv) * 64 + ln;
        int r = slot >> 2;
        int cg = (slot & 3) ^ ((r >> 1) & 3);
        aoff[i] = (size_t)(row0 + r) * KDIM + cg * 8;
    }
#pragma unroll
    for (int i = 0; i < 4; ++i) {
        int slot = (i * 4 + wv) * 64 + ln;
        int r = slot >> 2;
        int cg = (slot & 3) ^ ((r >> 1) & 3);
        boff[i] = (size_t)(col0 + r) * KDIM + cg * 8;
    }

    f32x4 acc[4][8];
#pragma unroll
    for (int m = 0; m < 4; ++m)
#pragma unroll
        for (int n = 0; n < 8; ++n) acc[m][n] = (f32x4){0.f, 0.f, 0.f, 0.f};

#define STAGE(buf, step)                                                            \
    do {                                                                            \
        int k0_ = (step) * 32;                                                      \
        _Pragma("unroll")                                                           \
        for (int i_ = 0; i_ < 2; ++i_)                                              \
            __builtin_amdgcn_global_load_lds(                                       \
                (const __attribute__((address_space(1))) void*)(xhi + aoff[i_] + k0_), \
                (__attribute__((address_space(3))) void*)&As[buf][(i_ * 4 + wv) * 512], \
                16, 0, 0);                                                          \
        _Pragma("unroll")                                                           \
        for (int i_ = 0; i_ < 4; ++i_)                                              \
            __builtin_amdgcn_global_load_lds(                                       \
                (const __attribute__((address_space(1))) void*)(ehi + boff[i_] + k0_), \
                (__attribute__((address_space(3))) void*)&Bs[buf][(i_ * 4 + wv) * 512], \
                16, 0, 0);                                                          \
    } while (0)

    STAGE(0, 0);
    __syncthreads();
    int cur = 0;
    const int swz = (hg ^ ((lr >> 1) & 3)) * 8;
    for (int step = 0; step < 16; ++step) {
        if (step < 15) STAGE(cur ^ 1, step + 1);
        bf16x8 a[4], b[8];
#pragma unroll
        for (int m = 0; m < 4; ++m)
            a[m] = *(const bf16x8*)&As[cur][(wr * 64 + m * 16 + lr) * 32 + swz];
#pragma unroll
        for (int n = 0; n < 8; ++n)
            b[n] = *(const bf16x8*)&Bs[cur][(wc * 128 + n * 16 + lr) * 32 + swz];
#pragma unroll
        for (int m = 0; m < 4; ++m)
#pragma unroll
            for (int n = 0; n < 8; ++n)
                acc[m][n] = __builtin_amdgcn_mfma_f32_16x16x32_bf16(a[m], b[n], acc[m][n], 0, 0, 0);
        __syncthreads();
        cur ^= 1;
    }
#undef STAGE

    // epilogue: per (m,r) slot TOP-2 over this wave's 128 cols (= one code block)
    const int colbase = col0 + wc * 128;
    const int cbw = cgrp * 2 + wc;
    float nrm[8];
#pragma unroll
    for (int n = 0; n < 8; ++n) nrm[n] = norms[colbase + n * 16 + lr];

#pragma unroll
    for (int m = 0; m < 4; ++m)
#pragma unroll
        for (int r = 0; r < 4; ++r) {
            ull k0 = ~0ull, k1 = ~0ull;
#pragma unroll
            for (int n = 0; n < 8; ++n) {
                float s = nrm[n] - 2.f * acc[m][n][r];
                ull key = ((ull)f2s(s) << 32) | (unsigned)(colbase + n * 16 + lr);
                if (key < k0) { k1 = k0; k0 = key; }
                else if (key < k1) { k1 = key; }
            }
#pragma unroll
            for (int off = 1; off < 16; off <<= 1) {
                ull o0 = __shfl_xor(k0, off, 64);
                ull o1 = __shfl_xor(k1, off, 64);
                ull mx = k0 > o0 ? k0 : o0;
                ull mn = k1 < o1 ? k1 : o1;
                k0 = k0 < o0 ? k0 : o0;
                k1 = mx < mn ? mx : mn;
            }
            if (lr == 0) {
                int row_out = row0 + wr * 64 + m * 16 + hg * 4 + r;
                part[(size_t)row_out * NCB + cbw] =
                    make_float4(s2f((unsigned)(k0 >> 32)),
                                __int_as_float((int)(k0 & 0xFFFFFFFFu)),
                                s2f((unsigned)(k1 >> 32)),
                                __int_as_float((int)(k1 & 0xFFFFFFFFu)));
            }
        }
}

// ---------------- kernel 5: fused exact refine + quantize gather + diff partial ----------------
// One wave per row; block = 4 rows. Candidates: top-2 per block with hi-score <= min+MARGIN,
// recomputed in exact fp32; winner's code row written to out; d^2 partial accumulated.
__global__ __launch_bounds__(256) void k_refine(const float* __restrict__ x,
                                                const float* __restrict__ et,
                                                const float* __restrict__ norms,
                                                const float4* __restrict__ part,
                                                float* __restrict__ out,
                                                float* __restrict__ dpart) {
    const int row = blockIdx.x * 4 + (threadIdx.x >> 6);
    const int lane = threadIdx.x & 63;

    float xv[8];
    *(float4*)&xv[0] = *(const float4*)(x + (size_t)row * KDIM + lane * 8);
    *(float4*)&xv[4] = *(const float4*)(x + (size_t)row * KDIM + lane * 8 + 4);

    const float* prowf = (const float*)(part + (size_t)row * NCB);
    float m = FLT_MAX;
    for (int cbi = 0; cbi < NCB; ++cbi) m = fminf(m, prowf[cbi * 4]);
    const float thr = m + MARGIN;

    float bs = FLT_MAX;
    int bj = 0x7FFFFFFF;
    const float4* prow = part + (size_t)row * NCB;
    for (int cbi = 0; cbi < NCB; ++cbi) {
        float4 p = prow[cbi];
#pragma unroll
        for (int t = 0; t < 2; ++t) {
            float sh = t ? p.z : p.x;
            int j = __float_as_int(t ? p.w : p.y);
            if (sh <= thr) {                       // wave-uniform branch
                const float* er = et + (size_t)j * KDIM + lane * 8;
                float ev[8];
                *(float4*)&ev[0] = *(const float4*)er;
                *(float4*)&ev[4] = *(const float4*)(er + 4);
                float d = 0.f;
#pragma unroll
                for (int q = 0; q < 8; ++q) d += xv[q] * ev[q];
#pragma unroll
                for (int off = 1; off < 64; off <<= 1) d += __shfl_xor(d, off, 64);
                float s = norms[j] - 2.f * d;      // exact fp32 score
                if (better(s, j, bs, bj)) { bs = s; bj = j; }
            }
        }
    }

    // winner: write quantize row + diff partial
    const float* er = et + (size_t)bj * KDIM + lane * 8;
    float ev[8];
    *(float4*)&ev[0] = *(const float4*)er;
    *(float4*)&ev[4] = *(const float4*)(er + 4);
    float dsum = 0.f;
#pragma unroll
    for (int q = 0; q < 8; ++q) {
        float d = ev[q] - xv[q];
        dsum += d * d;
    }
    *(float4*)(out + OUT_Q + (size_t)row * KDIM + lane * 8) = *(float4*)&ev[0];
    *(float4*)(out + OUT_Q + (size_t)row * KDIM + lane * 8 + 4) = *(float4*)&ev[4];
#pragma unroll
    for (int off = 1; off < 64; off <<= 1) dsum += __shfl_xor(dsum, off, 64);

    __shared__ float ds4[4];
    if (lane == 0) {
        out[OUT_IDX + row] = (float)bj;
        ds4[threadIdx.x >> 6] = dsum;
    }
    __syncthreads();
    if (threadIdx.x == 0)
        dpart[blockIdx.x] = ds4[0] + ds4[1] + ds4[2] + ds4[3];
}

// ---------------- fallback fp32 GEMM-argmin (ws-lean, round-1) ----------------
#define TMF 128
#define TNF 128
#define TKF 16
__global__ __launch_bounds__(256) void k_gemm_argmin(
        const float* __restrict__ x, const float* __restrict__ e,
        const float* __restrict__ norms, float2* __restrict__ part)
{
    __shared__ float xs[TKF][132];
    __shared__ float es[TKF][TNF];
    __shared__ float2 red[TMF][16];

    const int row0 = blockIdx.x * TMF, col0 = blockIdx.y * TNF;
    const int tid = threadIdx.x;
    const int ty = tid >> 4, tx = tid & 15;

    float acc[8][8];
#pragma unroll
    for (int i = 0; i < 8; ++i)
#pragma unroll
        for (int j = 0; j < 8; ++j) acc[i][j] = 0.f;

    for (int k0 = 0; k0 < KDIM; k0 += TKF) {
        __syncthreads();
#pragma unroll
        for (int s = 0; s < 2; ++s) {
            int slot = tid + s * 256;
            int r = slot >> 2, c4 = slot & 3;
            float4 v = *(const float4*)(x + (size_t)(row0 + r) * KDIM + k0 + c4 * 4);
            xs[c4 * 4 + 0][r] = v.x; xs[c4 * 4 + 1][r] = v.y;
            xs[c4 * 4 + 2][r] = v.z; xs[c4 * 4 + 3][r] = v.w;
        }
#pragma unroll
        for (int s = 0; s < 2; ++s) {
            int slot = tid + s * 256;
            int k = slot >> 5, c4 = slot & 31;
            *(float4*)(&es[k][c4 * 4]) =
                *(const float4*)(e + (size_t)(k0 + k) * NEMB + col0 + c4 * 4);
        }
        __syncthreads();
#pragma unroll
        for (int k = 0; k < TKF; ++k) {
            float xv[8], ev[8];
            *(float4*)&xv[0] = *(const float4*)&xs[k][ty * 8];
            *(float4*)&xv[4] = *(const float4*)&xs[k][ty * 8 + 4];
            *(float4*)&ev[0] = *(const float4*)&es[k][tx * 8];
            *(float4*)&ev[4] = *(const float4*)&es[k][tx * 8 + 4];
#pragma unroll
            for (int i = 0; i < 8; ++i)
#pragma unroll
                for (int j = 0; j < 8; ++j) acc[i][j] += xv[i] * ev[j];
        }
    }
    float nrm[8];
#pragma unroll
    for (int j = 0; j < 8; ++j) nrm[j] = norms[col0 + tx * 8 + j];
#pragma unroll
    for (int i = 0; i < 8; ++i) {
        float best = FLT_MAX; int bj = 0;
#pragma unroll
        for (int j = 0; j < 8; ++j) {
            float sc = nrm[j] - 2.f * acc[i][j];
            if (sc < best) { best = sc; bj = tx * 8 + j; }
        }
        red[ty * 8 + i][tx] = make_float2(best, __int_as_float(bj));
    }
    __syncthreads();
    if (tid < TMF) {
        float best = FLT_MAX; int bj = 0;
        for (int t = 0; t < 16; ++t) {
            float2 p = red[tid][t];
            if (p.x < best) { best = p.x; bj = __float_as_int(p.y); }
        }
        part[(size_t)(row0 + tid) * NCB + blockIdx.y] =
            make_float2(best, __int_as_float(col0 + bj));
    }
}

__global__ void k_transpose(const float* __restrict__ e, float* __restrict__ et) {
    __shared__ float t[32][33];
    int jb = blockIdx.x * 32, kb = blockIdx.y * 32;
    int tx = threadIdx.x, ty = threadIdx.y;
    for (int i = ty; i < 32; i += 8)
        t[i][tx] = e[(size_t)(kb + i) * NEMB + jb + tx];
    __syncthreads();
    for (int i = ty; i < 32; i += 8)
        et[(size_t)(jb + i) * KDIM + kb + tx] = t[tx][i];
}

__global__ __launch_bounds__(256) void k_reduce(const float2* __restrict__ part,
                                                int* __restrict__ idx_out,
                                                float* __restrict__ out) {
    int row = blockIdx.x * 256 + threadIdx.x;
    float best = FLT_MAX;
    int bj = 0x7FFFFFFF;
    for (int cbi = 0; cbi < NCB; ++cbi) {
        float2 p = part[(size_t)row * NCB + cbi];
        int c = __float_as_int(p.y);
        if (p.x < best || (p.x == best && c < bj)) { best = p.x; bj = c; }
    }
    idx_out[row] = bj;
    out[OUT_IDX + row] = (float)bj;
}

__global__ __launch_bounds__(256) void k_gather(const float* __restrict__ x,
                                                const float* __restrict__ et,
                                                const int* __restrict__ idx,
                                                float* __restrict__ out,
                                                float* __restrict__ dpart) {
    const int b = blockIdx.x;
    const int tid = threadIdx.x;
    const int row0 = b * 16;
    float s = 0.f;
    for (int i = tid; i < 16 * KDIM; i += 256) {
        int r = i >> 9;
        int k = i & (KDIM - 1);
        int row = row0 + r;
        float q = et[(size_t)idx[row] * KDIM + k];
        float xv = x[(size_t)row * KDIM + k];
        float d = q - xv;
        s += d * d;
        out[OUT_Q + (size_t)row * KDIM + k] = q;
    }
#pragma unroll
    for (int off = 32; off >= 1; off >>= 1) s += __shfl_down(s, off, 64);
    __shared__ float ws_[4];
    int lane = tid & 63, wvi = tid >> 6;
    if (lane == 0) ws_[wvi] = s;
    __syncthreads();
    if (tid == 0) dpart[b] = ws_[0] + ws_[1] + ws_[2] + ws_[3];
}

// ---------------- final diff over n partials ----------------
__global__ __launch_bounds__(256) void k_diff(const float* __restrict__ dpart, int n,
                                              float* __restrict__ out) {
    int tid = threadIdx.x;
    float s = 0.f;
    for (int i = tid; i < n; i += 256) s += dpart[i];
#pragma unroll
    for (int off = 32; off >= 1; off >>= 1) s += __shfl_down(s, off, 64);
    __shared__ float ws_[4];
    int lane = tid & 63, wvi = tid >> 6;
    if (lane == 0) ws_[wvi] = s;
    __syncthreads();
    if (tid == 0) out[OUT_DIFF] = (ws_[0] + ws_[1] + ws_[2] + ws_[3]) / 16777216.f;
}

extern "C" void kernel_launch(void* const* d_in, const int* in_sizes, int n_in,
                              void* d_out, int out_size, void* d_ws, size_t ws_size,
                              hipStream_t stream) {
    const float* x = (const float*)d_in[0];   // [8,4096,512]
    const float* e = (const float*)d_in[1];   // [512,4096]
    float* out = (float*)d_out;
    float* ws = (float*)d_ws;

    float*  norms = ws + OFF_NORMS;
    float*  et    = ws + OFF_ET;
    float*  dpart = ws + OFF_DP;

    k_norms<<<NEMB / 256, 256, 0, stream>>>(e, norms);

    if (ws_size >= (size_t)WS_FAST_FLOATS * 4) {
        float4* part = (float4*)(ws + OFF_PART);
        unsigned short* xhi = (unsigned short*)(ws + OFF_XHI);
        unsigned short* ehi = (unsigned short*)(ws + OFF_EHI);
        k_split_et<<<dim3(NEMB / 32, KDIM / 32), dim3(32, 8), 0, stream>>>(e, et, ehi);
        k_split_x<<<(NROWS * KDIM) / (256 * 4), 256, 0, stream>>>(x, xhi);
        k_mfma_argmin<<<4096, 256, 0, stream>>>(xhi, ehi, norms, part);
        k_refine<<<NROWS / 4, 256, 0, stream>>>(x, et, norms, part, out, dpart);
        k_diff<<<1, 256, 0, stream>>>(dpart, NROWS / 4, out);
    } else {
        float2* part2 = (float2*)(ws + OFF_PART);
        int* idx = (int*)(ws + OFF_IDX);
        k_transpose<<<dim3(NEMB / 32, KDIM / 32), dim3(32, 8), 0, stream>>>(e, et);
        k_gemm_argmin<<<dim3(NROWS / TMF, NEMB / TNF), 256, 0, stream>>>(x, e, norms, part2);
        k_reduce<<<NROWS / 256, 256, 0, stream>>>(part2, idx, out);
        k_gather<<<NROWS / 16, 256, 0, stream>>>(x, et, idx, out, dpart);
        k_diff<<<1, 256, 0, stream>>>(dpart, NROWS / 16, out);
    }
}